// Round 5
// baseline (76659.521 us; speedup 1.0000x reference)
//
#include <hip/hip_runtime.h>
#include <stdint.h>

#define BATCH 256
#define SEQT  512
#define DIM   128
#define HID   256
#define G3    768   // 3*HID

typedef unsigned short u16;
typedef unsigned int   u32;
typedef u16 u16x8 __attribute__((ext_vector_type(8)));
typedef float f32x4 __attribute__((ext_vector_type(4)));

static __device__ __forceinline__ float bflo(u32 w) { return __builtin_bit_cast(float, w << 16); }
static __device__ __forceinline__ float bfhi(u32 w) { return __builtin_bit_cast(float, w & 0xFFFF0000u); }
static __device__ __forceinline__ u16 f2bf(float f) {
  u32 x = __builtin_bit_cast(u32, f);
  x += 0x7FFFu + ((x >> 16) & 1u);
  return (u16)(x >> 16);
}
static __device__ __forceinline__ float sigm(float v) {
  return 1.f / (1.f + __expf(-v));
}
static __device__ __forceinline__ void unpack8(u16x8 wv, float* f) {
  u32 w0 = (u32)wv[0] | ((u32)wv[1] << 16);
  u32 w1 = (u32)wv[2] | ((u32)wv[3] << 16);
  u32 w2 = (u32)wv[4] | ((u32)wv[5] << 16);
  u32 w3 = (u32)wv[6] | ((u32)wv[7] << 16);
  f[0] = bflo(w0); f[1] = bfhi(w0); f[2] = bflo(w1); f[3] = bfhi(w1);
  f[4] = bflo(w2); f[5] = bfhi(w2); f[6] = bflo(w3); f[7] = bfhi(w3);
}
static __device__ __forceinline__ void fma8(float& acc, const float* f, float4 a, float4 b) {
  acc += f[0]*a.x + f[1]*a.y + f[2]*a.z + f[3]*a.w +
         f[4]*b.x + f[5]*b.y + f[6]*b.z + f[7]*b.w;
}

// ---------------- weight fp32 -> bf16 conversion ----------------
__global__ void convertk(const float* __restrict__ src, u16* __restrict__ dst, int n) {
  int i = blockIdx.x * 256 + threadIdx.x;
  if (i < n) dst[i] = f2bf(src[i]);
}

// ---------------- phase B: memory GRU, 4 batch rows per block, 768 threads ----------------
// thread = gate-row: q=tid>>8 (0=r,1=z,2=n), c=tid&255; each thread computes 4 dots (rows b0..b0+3)
__launch_bounds__(768, 3)
__global__ void gru_mem4(const float* __restrict__ x,
                         const u16* __restrict__ Wib, const u16* __restrict__ Whb,
                         const float* __restrict__ bmi, const float* __restrict__ bmh,
                         u16* __restrict__ mem) {
  const int b0 = blockIdx.x * 4, tid = threadIdx.x;
  const int q = tid >> 8, c = tid & 255;
  __shared__ __align__(16) float xs[4][DIM];
  __shared__ __align__(16) float hsm[4][HID];
  __shared__ __align__(16) float rs[4][HID], zs[4][HID];

  float Brz = 0.f, Bni = 0.f, Bnh = 0.f;
  if (q < 2) { int rw = q * HID + c; Brz = bmi[rw] + bmh[rw]; }
  else       { int rw = 2 * HID + c; Bni = bmi[rw]; Bnh = bmh[rw]; }
  const u16x8* wi = (const u16x8*)(Wib + (size_t)(q * HID + c) * DIM);
  const u16x8* wh = (const u16x8*)(Whb + (size_t)(q * HID + c) * HID);
  float hprev[4] = {0.f, 0.f, 0.f, 0.f};
  if (q == 0) { hsm[0][c] = 0.f; hsm[1][c] = 0.f; hsm[2][c] = 0.f; hsm[3][c] = 0.f; }
  __syncthreads();

  for (int t = 0; t < SEQT; ++t) {
    if (tid < 128)
      ((f32x4*)xs[tid >> 5])[tid & 31] = __builtin_nontemporal_load(
          ((const f32x4*)(x + ((size_t)(b0 + (tid >> 5)) * SEQT + t) * DIM)) + (tid & 31));
    __syncthreads();               // xs ready; hsm stable
    float ax[4] = {0.f,0.f,0.f,0.f}, ah[4] = {0.f,0.f,0.f,0.f};
    float f[8];
    #pragma unroll 2
    for (int j = 0; j < DIM / 8; ++j) {
      unpack8(wi[j], f);
      #pragma unroll
      for (int r = 0; r < 4; ++r) {
        const float4* a4 = (const float4*)xs[r];
        fma8(ax[r], f, a4[2*j], a4[2*j+1]);
      }
    }
    #pragma unroll 2
    for (int j = 0; j < HID / 8; ++j) {
      unpack8(wh[j], f);
      #pragma unroll
      for (int r = 0; r < 4; ++r) {
        const float4* a4 = (const float4*)hsm[r];
        fma8(ah[r], f, a4[2*j], a4[2*j+1]);
      }
    }
    if (q < 2) {
      #pragma unroll
      for (int r = 0; r < 4; ++r) {
        float g = sigm(ax[r] + ah[r] + Brz);
        (q ? zs : rs)[r][c] = g;
      }
    }
    __syncthreads();               // rs, zs ready; hsm reads done
    if (q == 2) {
      #pragma unroll
      for (int r = 0; r < 4; ++r) {
        float nn = tanhf(ax[r] + Bni + rs[r][c] * (ah[r] + Bnh));
        float h = (1.f - zs[r][c]) * nn + zs[r][c] * hprev[r];
        hprev[r] = h;
        hsm[r][c] = h;
        mem[((size_t)(b0 + r) * SEQT + t) * HID + c] = f2bf(h);
      }
    }
    __syncthreads();               // hsm ready for next step
  }
}

// ---------------- decoder cell: weight-shared 4-row feed-forward GRU cell ----------------
template <int IN>
static __device__ __forceinline__ void cell4(const float* __restrict__ actIn,  // [4][IN]
                                             float* __restrict__ actOut,       // [4][256]
                                             const u16* __restrict__ Wb,
                                             int q, int c,
                                             float Brz, float Bni, float Bnh,
                                             float (* __restrict__ rs)[HID],
                                             float (* __restrict__ zs)[HID]) {
  float acc[4] = {0.f, 0.f, 0.f, 0.f};
  if (q < 3) {
    const u16x8* w = (const u16x8*)(Wb + (size_t)(q * HID + c) * IN);
    float f[8];
    #pragma unroll 4
    for (int j = 0; j < IN / 8; ++j) {
      unpack8(w[j], f);
      #pragma unroll
      for (int r = 0; r < 4; ++r) {
        const float4* a4 = (const float4*)(actIn + r * IN);
        fma8(acc[r], f, a4[2*j], a4[2*j+1]);
      }
    }
    if (q < 2) {
      #pragma unroll
      for (int r = 0; r < 4; ++r) {
        float g = sigm(acc[r] + Brz);
        (q ? zs : rs)[r][c] = g;
      }
    }
  }
  __syncthreads();                 // rs, zs ready
  if (q == 2) {
    #pragma unroll
    for (int r = 0; r < 4; ++r)
      actOut[r * HID + c] = (1.f - zs[r][c]) * tanhf(acc[r] + Bni + rs[r][c] * Bnh);
  }
  __syncthreads();                 // actOut ready
}

// ---------------- phase C: decoder scan, 4 batch rows per block, 1024 threads ----------------
__launch_bounds__(1024, 4)
__global__ void decoder4(const float* __restrict__ x, const u16* __restrict__ mem,
                         const u16* __restrict__ W0b, const u16* __restrict__ W1b,
                         const u16* __restrict__ W2b, const u16* __restrict__ W3b,
                         const u16* __restrict__ W4b,
                         const float* __restrict__ bi0, const float* __restrict__ bh0,
                         const float* __restrict__ bi1, const float* __restrict__ bh1,
                         const float* __restrict__ bi2, const float* __restrict__ bh2,
                         const float* __restrict__ bi3, const float* __restrict__ bh3,
                         const float* __restrict__ bi4, const float* __restrict__ bh4,
                         const float* __restrict__ Wo, const float* __restrict__ bo,
                         float* __restrict__ out) {
  const int b0 = blockIdx.x * 4, tid = threadIdx.x;
  const int wave = tid >> 6;
  const int q = tid >> 8, c = tid & 255;     // attention: group q, row b0+q; cells: gate q (q==3 idle)
  __shared__ __align__(16) float pp[4][512];
  __shared__ __align__(16) float pvp[4][2][HID];
  __shared__ __align__(16) float kst[4][HID];
  __shared__ __align__(16) float dv[4][DIM + HID];
  __shared__ __align__(16) float hA[4][HID], hB[4][HID];
  __shared__ __align__(16) float rs[4][HID], zs[4][HID];
  __shared__ float red[16], red2[16];

  float Brz[5] = {0,0,0,0,0}, Bni[5] = {0,0,0,0,0}, Bnh[5] = {0,0,0,0,0};
  if (q < 2) {
    int rw = q * HID + c;
    Brz[0] = bi0[rw] + bh0[rw]; Brz[1] = bi1[rw] + bh1[rw]; Brz[2] = bi2[rw] + bh2[rw];
    Brz[3] = bi3[rw] + bh3[rw]; Brz[4] = bi4[rw] + bh4[rw];
  } else if (q == 2) {
    int rw = 2 * HID + c;
    Bni[0] = bi0[rw]; Bnh[0] = bh0[rw]; Bni[1] = bi1[rw]; Bnh[1] = bh1[rw];
    Bni[2] = bi2[rw]; Bnh[2] = bh2[rw]; Bni[3] = bi3[rw]; Bnh[3] = bh3[rw];
    Bni[4] = bi4[rw]; Bnh[4] = bh4[rw];
  }
  float wo0 = 0.f, wo1 = 0.f, wo2 = 0.f, wo3 = 0.f;
  const float bo0 = bo[0];
  const int gl = tid & 63;
  if (((tid >> 6) & 3) == 0) { wo0 = Wo[gl]; wo1 = Wo[64+gl]; wo2 = Wo[128+gl]; wo3 = Wo[192+gl]; }
  kst[q][c] = 0.f;
  __syncthreads();

  const u16* mg = mem + (size_t)(b0 + q) * SEQT * HID;
  const u32* mg32 = (const u32*)mg;
  const int sh = (tid >> 7) & 1, cp = tid & 127;   // PV: s-half, column pair

  for (int t = 0; t < SEQT; ++t) {
    // x prefetch (regs)
    f32x4 xv;
    if (tid < 128)
      xv = __builtin_nontemporal_load(
          ((const f32x4*)(x + ((size_t)(b0 + (tid >> 5)) * SEQT + t) * DIM)) + (tid & 31));

    // ---- pass 1: scores (thread owns positions c, c+256 of its group's row) ----
    float s0 = 0.f, s1 = 0.f;
    {
      const u16x8* m0 = (const u16x8*)(mg + (size_t)c * HID);
      const u16x8* m1 = (const u16x8*)(mg + (size_t)(c + 256) * HID);
      const float4* k4 = (const float4*)kst[q];
      float f[8];
      #pragma unroll 8
      for (int j = 0; j < HID / 8; ++j) {
        float4 ka = k4[2*j], kb = k4[2*j+1];
        unpack8(m0[j], f); fma8(s0, f, ka, kb);
        unpack8(m1[j], f); fma8(s1, f, ka, kb);
      }
    }
    float mloc = fmaxf(s0, s1);
    #pragma unroll
    for (int off = 32; off; off >>= 1) mloc = fmaxf(mloc, __shfl_xor(mloc, off));
    if ((tid & 63) == 0) red[wave] = mloc;
    if (tid < 128) ((f32x4*)dv[tid >> 5])[tid & 31] = xv;
    __syncthreads();               // S1: red, dv-x

    float mm = fmaxf(fmaxf(red[q*4], red[q*4+1]), fmaxf(red[q*4+2], red[q*4+3]));
    float p0 = __expf(s0 - mm), p1 = __expf(s1 - mm);
    pp[q][c] = p0; pp[q][c + 256] = p1;
    float ls = p0 + p1;
    #pragma unroll
    for (int off = 32; off; off >>= 1) ls += __shfl_xor(ls, off);
    if ((tid & 63) == 0) red2[wave] = ls;
    __syncthreads();               // S2: pp, red2

    // ---- pass 2: PV from global (coalesced: wave spans contiguous 256B of a row) ----
    float ctx0 = 0.f, ctx1 = 0.f;
    {
      const float* ppg = &pp[q][sh * 256];
      const u32* mcol = mg32 + (size_t)sh * 256 * 128 + cp;
      #pragma unroll 8
      for (int p = 0; p < 256; p += 8) {
        float4 pa = *(const float4*)(ppg + p);
        float4 pb = *(const float4*)(ppg + p + 4);
        u32 a0 = mcol[(size_t)(p+0)*128]; u32 a1 = mcol[(size_t)(p+1)*128];
        u32 a2 = mcol[(size_t)(p+2)*128]; u32 a3 = mcol[(size_t)(p+3)*128];
        u32 a4 = mcol[(size_t)(p+4)*128]; u32 a5 = mcol[(size_t)(p+5)*128];
        u32 a6 = mcol[(size_t)(p+6)*128]; u32 a7 = mcol[(size_t)(p+7)*128];
        ctx0 += pa.x*bflo(a0); ctx1 += pa.x*bfhi(a0);
        ctx0 += pa.y*bflo(a1); ctx1 += pa.y*bfhi(a1);
        ctx0 += pa.z*bflo(a2); ctx1 += pa.z*bfhi(a2);
        ctx0 += pa.w*bflo(a3); ctx1 += pa.w*bfhi(a3);
        ctx0 += pb.x*bflo(a4); ctx1 += pb.x*bfhi(a4);
        ctx0 += pb.y*bflo(a5); ctx1 += pb.y*bfhi(a5);
        ctx0 += pb.z*bflo(a6); ctx1 += pb.z*bfhi(a6);
        ctx0 += pb.w*bflo(a7); ctx1 += pb.w*bfhi(a7);
      }
      pvp[q][sh][2*cp]     = ctx0;
      pvp[q][sh][2*cp + 1] = ctx1;
    }
    __syncthreads();               // S3: pvp

    {
      float ls2 = red2[q*4] + red2[q*4+1] + red2[q*4+2] + red2[q*4+3];
      dv[q][DIM + c] = (pvp[q][0][c] + pvp[q][1][c]) / ls2;
    }
    __syncthreads();               // S4: dv complete

    // ---- 5 weight-shared feed-forward GRU cells ----
    cell4<DIM + HID>(&dv[0][0], &hA[0][0], W0b, q, c, Brz[0], Bni[0], Bnh[0], rs, zs);
    cell4<HID>(&hA[0][0], &hB[0][0], W1b, q, c, Brz[1], Bni[1], Bnh[1], rs, zs);
    cell4<HID>(&hB[0][0], &hA[0][0], W2b, q, c, Brz[2], Bni[2], Bnh[2], rs, zs);
    cell4<HID>(&hA[0][0], &hB[0][0], W3b, q, c, Brz[3], Bni[3], Bnh[3], rs, zs);
    cell4<HID>(&hB[0][0], &kst[0][0], W4b, q, c, Brz[4], Bni[4], Bnh[4], rs, zs);

    // ---- output layer: each group's wave 0 ----
    if (((tid >> 6) & 3) == 0) {
      float acc = kst[q][gl] * wo0 + kst[q][64 + gl] * wo1 +
                  kst[q][128 + gl] * wo2 + kst[q][192 + gl] * wo3;
      #pragma unroll
      for (int off = 32; off; off >>= 1) acc += __shfl_xor(acc, off);
      if (gl == 0) out[(size_t)(b0 + q) * SEQT + t] = sigm(acc + bo0);
    }
  }
}

// ---------------- host ----------------
extern "C" void kernel_launch(void* const* d_in, const int* in_sizes, int n_in,
                              void* d_out, int out_size, void* d_ws, size_t ws_size,
                              hipStream_t stream) {
  const float* x    = (const float*)d_in[0];
  const float* Wmi  = (const float*)d_in[1];
  const float* Wmh  = (const float*)d_in[2];
  const float* bmi  = (const float*)d_in[3];
  const float* bmh  = (const float*)d_in[4];
  const float* Wd0  = (const float*)d_in[5];
  const float* bi0  = (const float*)d_in[6];
  const float* bh0  = (const float*)d_in[7];
  const float* Wd1  = (const float*)d_in[8];
  const float* bi1  = (const float*)d_in[9];
  const float* bh1  = (const float*)d_in[10];
  const float* Wd2  = (const float*)d_in[11];
  const float* bi2  = (const float*)d_in[12];
  const float* bh2  = (const float*)d_in[13];
  const float* Wk0  = (const float*)d_in[14];
  const float* bik0 = (const float*)d_in[15];
  const float* bhk0 = (const float*)d_in[16];
  const float* Wk1  = (const float*)d_in[17];
  const float* bik1 = (const float*)d_in[18];
  const float* bhk1 = (const float*)d_in[19];
  const float* Wo   = (const float*)d_in[20];
  const float* bo   = (const float*)d_in[21];

  u16* mem = (u16*)d_ws;
  size_t off = (size_t)BATCH * SEQT * HID;     // u16 units
  u16* Wmib = mem + off; off += (size_t)G3 * DIM;
  u16* Wmhb = mem + off; off += (size_t)G3 * HID;
  u16* W0b  = mem + off; off += (size_t)G3 * (DIM + HID);
  u16* W1b  = mem + off; off += (size_t)G3 * HID;
  u16* W2b  = mem + off; off += (size_t)G3 * HID;
  u16* W3b  = mem + off; off += (size_t)G3 * HID;
  u16* W4b  = mem + off; off += (size_t)G3 * HID;
  (void)ws_size; (void)in_sizes; (void)n_in; (void)out_size;

  convertk<<<(G3*DIM + 255) / 256, 256, 0, stream>>>(Wmi, Wmib, G3*DIM);
  convertk<<<(G3*HID + 255) / 256, 256, 0, stream>>>(Wmh, Wmhb, G3*HID);
  convertk<<<(G3*(DIM+HID) + 255) / 256, 256, 0, stream>>>(Wd0, W0b, G3*(DIM+HID));
  convertk<<<(G3*HID + 255) / 256, 256, 0, stream>>>(Wd1, W1b, G3*HID);
  convertk<<<(G3*HID + 255) / 256, 256, 0, stream>>>(Wd2, W2b, G3*HID);
  convertk<<<(G3*HID + 255) / 256, 256, 0, stream>>>(Wk0, W3b, G3*HID);
  convertk<<<(G3*HID + 255) / 256, 256, 0, stream>>>(Wk1, W4b, G3*HID);

  gru_mem4<<<BATCH / 4, 768, 0, stream>>>(x, Wmib, Wmhb, bmi, bmh, mem);
  decoder4<<<BATCH / 4, 1024, 0, stream>>>(x, mem, W0b, W1b, W2b, W3b, W4b,
                                           bi0, bh0, bi1, bh1, bi2, bh2,
                                           bik0, bhk0, bik1, bhk1, Wo, bo,
                                           (float*)d_out);
}

// Round 6
// 22942.543 us; speedup vs baseline: 3.3414x; 3.3414x over previous
//
#include <hip/hip_runtime.h>
#include <stdint.h>

#define BATCH 256
#define SEQT  512
#define DIM   128
#define HID   256
#define G3    768   // 3*HID

typedef unsigned short u16;
typedef unsigned int   u32;
typedef _Float16 f16;
typedef f16 f16x2 __attribute__((ext_vector_type(2)));
typedef u32 u32x4v __attribute__((ext_vector_type(4)));
typedef float f32x4 __attribute__((ext_vector_type(4)));

static __device__ __forceinline__ u16 f2h(float f) {
  f16 h = (f16)f; return __builtin_bit_cast(u16, h);
}
static __device__ __forceinline__ float h2f(u16 u) {
  return (float)__builtin_bit_cast(f16, u);
}
static __device__ __forceinline__ float sigm(float v) {
  return 1.f / (1.f + __expf(-v));
}

// 2-MAC f16 dot with f32 accumulate
static __device__ __forceinline__ float dot2f(u32 a, u32 b, float acc) {
#if __has_builtin(__builtin_amdgcn_fdot2)
  return __builtin_amdgcn_fdot2(__builtin_bit_cast(f16x2, a),
                                __builtin_bit_cast(f16x2, b), acc, false);
#else
  f16x2 av = __builtin_bit_cast(f16x2, a), bv = __builtin_bit_cast(f16x2, b);
  return acc + (float)av[0] * (float)bv[0] + (float)av[1] * (float)bv[1];
#endif
}
// 8 MACs, dual accumulator (breaks dependency chain)
static __device__ __forceinline__ void dot8q(float& a0, float& a1, u32x4v w, u32x4v a) {
  a0 = dot2f(w.x, a.x, a0);
  a1 = dot2f(w.y, a.y, a1);
  a0 = dot2f(w.z, a.z, a0);
  a1 = dot2f(w.w, a.w, a1);
}

// ---------------- weight fp32 -> f16, chunk-major transpose ----------------
// dst[((q*chunks + j)*256 + c)*8 + e] = f16( src[(q*256+c)*IN + j*8 + e] )
__global__ void convertT(const float* __restrict__ src, u16* __restrict__ dst,
                         int IN, int chunks, int total) {
  int t = blockIdx.x * 256 + threadIdx.x;
  if (t >= total) return;
  int e = t & 7, c = (t >> 3) & 255, r = t >> 11;
  int j = r % chunks, q = r / chunks;
  dst[t] = f2h(src[(size_t)(q * 256 + c) * IN + j * 8 + e]);
}

// ---------------- phase B: memory GRU, 768 threads, one block per batch row ----------------
__launch_bounds__(768)
__global__ void gru_memk(const float* __restrict__ x,
                         const u16* __restrict__ WiT, const u16* __restrict__ WhT,
                         const float* __restrict__ bmi, const float* __restrict__ bmh,
                         u16* __restrict__ mem) {
  const int b = blockIdx.x, tid = threadIdx.x;
  const int q = tid >> 8, c = tid & 255;
  __shared__ __align__(16) u16 xsH[DIM];
  __shared__ __align__(16) u16 hsH[HID];
  __shared__ __align__(16) float rs[HID], zs[HID];

  float Brz = 0.f, Bni = 0.f, Bnh = 0.f;
  if (q < 2) { int rw = q * HID + c; Brz = bmi[rw] + bmh[rw]; }
  else       { int rw = 2 * HID + c; Bni = bmi[rw]; Bnh = bmh[rw]; }
  const u32x4v* wi = (const u32x4v*)WiT + (size_t)q * (DIM / 8) * 256 + c;
  const u32x4v* wh = (const u32x4v*)WhT + (size_t)q * (HID / 8) * 256 + c;
  float hprev = 0.f;
  if (tid < HID) hsH[tid] = 0;
  __syncthreads();

  for (int t = 0; t < SEQT; ++t) {
    if (tid < DIM)
      xsH[tid] = f2h(__builtin_nontemporal_load(x + ((size_t)b * SEQT + t) * DIM + tid));
    __syncthreads();               // xsH ready; hsH stable
    float ax0 = 0.f, ax1 = 0.f, ah0 = 0.f, ah1 = 0.f;
    const u32x4v* xa = (const u32x4v*)xsH;
    const u32x4v* ha = (const u32x4v*)hsH;
    #pragma unroll 4
    for (int j = 0; j < DIM / 8; ++j) dot8q(ax0, ax1, wi[(size_t)j * 256], xa[j]);
    #pragma unroll 4
    for (int j = 0; j < HID / 8; ++j) dot8q(ah0, ah1, wh[(size_t)j * 256], ha[j]);
    float ax = ax0 + ax1, ah = ah0 + ah1;
    if (q < 2) (q ? zs : rs)[c] = sigm(ax + ah + Brz);
    __syncthreads();               // rs/zs ready; hsH reads done
    if (q == 2) {
      float nn = tanhf(ax + Bni + rs[c] * (ah + Bnh));
      float h = (1.f - zs[c]) * nn + zs[c] * hprev;
      hprev = h;
      hsH[c] = f2h(h);
      mem[((size_t)b * SEQT + t) * HID + c] = f2h(h);
    }
    __syncthreads();               // hsH ready
  }
}

// ---------------- decoder feed-forward cell ----------------
template <int IN>
static __device__ __forceinline__ void cellT(const u16* __restrict__ inH,
                                             u16* __restrict__ outH,
                                             const u16* __restrict__ WT,
                                             int q, int c,
                                             float Brz, float Bni, float Bnh,
                                             float* __restrict__ rs, float* __restrict__ zs) {
  float a0 = 0.f, a1 = 0.f;
  if (q < 3) {
    const u32x4v* w = (const u32x4v*)WT + (size_t)q * (IN / 8) * 256 + c;
    const u32x4v* av = (const u32x4v*)inH;
    #pragma unroll 4
    for (int j = 0; j < IN / 8; ++j) dot8q(a0, a1, w[(size_t)j * 256], av[j]);
    if (q < 2) (q ? zs : rs)[c] = sigm(a0 + a1 + Brz);
  }
  __syncthreads();                 // rs/zs ready
  if (q == 2)
    outH[c] = f2h((1.f - zs[c]) * tanhf(a0 + a1 + Bni + rs[c] * Bnh));
  __syncthreads();                 // outH ready
}

// ---------------- phase C: decoder scan, 1024 threads, one block per batch row ----------------
__launch_bounds__(1024)
__global__ void decoderk(const float* __restrict__ x, const u16* __restrict__ memH,
                         const u16* __restrict__ W0T, const u16* __restrict__ W1T,
                         const u16* __restrict__ W2T, const u16* __restrict__ W3T,
                         const u16* __restrict__ W4T,
                         const float* __restrict__ bi0, const float* __restrict__ bh0,
                         const float* __restrict__ bi1, const float* __restrict__ bh1,
                         const float* __restrict__ bi2, const float* __restrict__ bh2,
                         const float* __restrict__ bi3, const float* __restrict__ bh3,
                         const float* __restrict__ bi4, const float* __restrict__ bh4,
                         const float* __restrict__ Wo, const float* __restrict__ bo,
                         float* __restrict__ out) {
  const int b = blockIdx.x, tid = threadIdx.x;
  const int lane = tid & 63, wave = tid >> 6;
  const int q = tid >> 8, c = tid & 255;
  __shared__ __align__(16) u16 kstH[HID];
  __shared__ __align__(16) u16 dvH[DIM + HID];
  __shared__ __align__(16) u16 hAH[HID], hBH[HID];
  __shared__ __align__(16) float rs[HID], zs[HID];
  __shared__ __align__(16) float ppF[512];
  __shared__ __align__(16) float pvp[8][HID];
  __shared__ float red[16], red2[16];

  float Brz[5] = {0,0,0,0,0}, Bni[5] = {0,0,0,0,0}, Bnh[5] = {0,0,0,0,0};
  if (q < 2) {
    int rw = q * HID + c;
    Brz[0] = bi0[rw] + bh0[rw]; Brz[1] = bi1[rw] + bh1[rw]; Brz[2] = bi2[rw] + bh2[rw];
    Brz[3] = bi3[rw] + bh3[rw]; Brz[4] = bi4[rw] + bh4[rw];
  } else if (q == 2) {
    int rw = 2 * HID + c;
    Bni[0] = bi0[rw]; Bnh[0] = bh0[rw]; Bni[1] = bi1[rw]; Bnh[1] = bh1[rw];
    Bni[2] = bi2[rw]; Bnh[2] = bh2[rw]; Bni[3] = bi3[rw]; Bnh[3] = bh3[rw];
    Bni[4] = bi4[rw]; Bnh[4] = bh4[rw];
  }
  float wo0 = 0.f, wo1 = 0.f, wo2 = 0.f, wo3 = 0.f;
  const float bo0 = bo[0];
  if (wave == 0) { wo0 = Wo[lane]; wo1 = Wo[64+lane]; wo2 = Wo[128+lane]; wo3 = Wo[192+lane]; }
  if (tid < HID) kstH[tid] = 0;
  __syncthreads();

  const u16* mb = memH + (size_t)b * SEQT * HID;
  const int p = tid >> 1, hf = tid & 1;      // scores
  const int sg = tid >> 7, cp = tid & 127;   // PV

  for (int t = 0; t < SEQT; ++t) {
    // x prefetch (consumed before S2)
    float xr = 0.f;
    if (tid < DIM)
      xr = __builtin_nontemporal_load(x + ((size_t)b * SEQT + t) * DIM + tid);

    // ---- scores: thread = (position p, half hf) ----
    float s0 = 0.f, s1 = 0.f;
    {
      const u32x4v* mr = (const u32x4v*)(mb + (size_t)p * HID) + hf * 16;
      const u32x4v* kq = ((const u32x4v*)kstH) + hf * 16;
      #pragma unroll 4
      for (int j = 0; j < 16; ++j) dot8q(s0, s1, mr[j], kq[j]);
    }
    float s = s0 + s1;
    s += __shfl_xor(s, 1);
    float mloc = s;
    #pragma unroll
    for (int off = 32; off; off >>= 1) mloc = fmaxf(mloc, __shfl_xor(mloc, off));
    if (lane == 0) red[wave] = mloc;
    __syncthreads();               // S1: red
    float m = red[0];
    #pragma unroll
    for (int i = 1; i < 16; ++i) m = fmaxf(m, red[i]);
    float pw = __expf(s - m);
    if (!hf) ppF[p] = pw;
    float ls = hf ? 0.f : pw;
    #pragma unroll
    for (int off = 32; off; off >>= 1) ls += __shfl_xor(ls, off);
    if (lane == 0) red2[wave] = ls;
    if (tid < DIM) dvH[tid] = f2h(xr);
    __syncthreads();               // S2: ppF, dv-x

    // ---- PV: thread = (s-eighth sg, column pair cp); coalesced global reads ----
    float c0 = 0.f, c1 = 0.f;
    {
      const u32* mc = (const u32*)mb + (size_t)sg * 64 * 128 + cp;
      const float* ppg = ppF + sg * 64;
      #pragma unroll 8
      for (int pj = 0; pj < 64; ++pj) {
        u32 v = mc[(size_t)pj * 128];
        float w2 = ppg[pj];
        f16x2 hv = __builtin_bit_cast(f16x2, v);
        c0 += w2 * (float)hv[0];
        c1 += w2 * (float)hv[1];
      }
      pvp[sg][2 * cp]     = c0;
      pvp[sg][2 * cp + 1] = c1;
    }
    __syncthreads();               // S3: pvp
    if (tid < HID) {
      float lsum = red2[0];
      #pragma unroll
      for (int i = 1; i < 16; ++i) lsum += red2[i];
      float ctx = pvp[0][tid] + pvp[1][tid] + pvp[2][tid] + pvp[3][tid] +
                  pvp[4][tid] + pvp[5][tid] + pvp[6][tid] + pvp[7][tid];
      dvH[DIM + tid] = f2h(ctx / lsum);
    }
    __syncthreads();               // S4: dv complete

    // ---- 5 feed-forward GRU cells ----
    cellT<DIM + HID>(dvH, hAH, W0T, q, c, Brz[0], Bni[0], Bnh[0], rs, zs);
    cellT<HID>(hAH, hBH, W1T, q, c, Brz[1], Bni[1], Bnh[1], rs, zs);
    cellT<HID>(hBH, hAH, W2T, q, c, Brz[2], Bni[2], Bnh[2], rs, zs);
    cellT<HID>(hAH, hBH, W3T, q, c, Brz[3], Bni[3], Bnh[3], rs, zs);
    cellT<HID>(hBH, kstH, W4T, q, c, Brz[4], Bni[4], Bnh[4], rs, zs);

    // ---- output layer (wave 0) ----
    if (wave == 0) {
      float acc = h2f(kstH[lane]) * wo0 + h2f(kstH[64 + lane]) * wo1 +
                  h2f(kstH[128 + lane]) * wo2 + h2f(kstH[192 + lane]) * wo3;
      #pragma unroll
      for (int off = 32; off; off >>= 1) acc += __shfl_xor(acc, off);
      if (lane == 0) out[(size_t)b * SEQT + t] = sigm(acc + bo0);
    }
  }
}

// ---------------- host ----------------
extern "C" void kernel_launch(void* const* d_in, const int* in_sizes, int n_in,
                              void* d_out, int out_size, void* d_ws, size_t ws_size,
                              hipStream_t stream) {
  const float* x    = (const float*)d_in[0];
  const float* Wmi  = (const float*)d_in[1];
  const float* Wmh  = (const float*)d_in[2];
  const float* bmi  = (const float*)d_in[3];
  const float* bmh  = (const float*)d_in[4];
  const float* Wd0  = (const float*)d_in[5];
  const float* bi0  = (const float*)d_in[6];
  const float* bh0  = (const float*)d_in[7];
  const float* Wd1  = (const float*)d_in[8];
  const float* bi1  = (const float*)d_in[9];
  const float* bh1  = (const float*)d_in[10];
  const float* Wd2  = (const float*)d_in[11];
  const float* bi2  = (const float*)d_in[12];
  const float* bh2  = (const float*)d_in[13];
  const float* Wk0  = (const float*)d_in[14];
  const float* bik0 = (const float*)d_in[15];
  const float* bhk0 = (const float*)d_in[16];
  const float* Wk1  = (const float*)d_in[17];
  const float* bik1 = (const float*)d_in[18];
  const float* bhk1 = (const float*)d_in[19];
  const float* Wo   = (const float*)d_in[20];
  const float* bo   = (const float*)d_in[21];

  u16* mem = (u16*)d_ws;
  size_t off = (size_t)BATCH * SEQT * HID;     // u16 units
  u16* WmiT = mem + off; off += (size_t)G3 * DIM;
  u16* WmhT = mem + off; off += (size_t)G3 * HID;
  u16* W0T  = mem + off; off += (size_t)G3 * (DIM + HID);
  u16* W1T  = mem + off; off += (size_t)G3 * HID;
  u16* W2T  = mem + off; off += (size_t)G3 * HID;
  u16* W3T  = mem + off; off += (size_t)G3 * HID;
  u16* W4T  = mem + off; off += (size_t)G3 * HID;
  (void)ws_size; (void)in_sizes; (void)n_in; (void)out_size;

  // chunk-major f16 weight transposes
  convertT<<<(G3*DIM + 255) / 256, 256, 0, stream>>>(Wmi, WmiT, DIM, DIM/8, G3*DIM);
  convertT<<<(G3*HID + 255) / 256, 256, 0, stream>>>(Wmh, WmhT, HID, HID/8, G3*HID);
  convertT<<<(G3*(DIM+HID) + 255) / 256, 256, 0, stream>>>(Wd0, W0T, DIM+HID, (DIM+HID)/8, G3*(DIM+HID));
  convertT<<<(G3*HID + 255) / 256, 256, 0, stream>>>(Wd1, W1T, HID, HID/8, G3*HID);
  convertT<<<(G3*HID + 255) / 256, 256, 0, stream>>>(Wd2, W2T, HID, HID/8, G3*HID);
  convertT<<<(G3*HID + 255) / 256, 256, 0, stream>>>(Wk0, W3T, HID, HID/8, G3*HID);
  convertT<<<(G3*HID + 255) / 256, 256, 0, stream>>>(Wk1, W4T, HID, HID/8, G3*HID);

  gru_memk<<<BATCH, 768, 0, stream>>>(x, WmiT, WmhT, bmi, bmh, mem);
  decoderk<<<BATCH, 1024, 0, stream>>>(x, mem, W0T, W1T, W2T, W3T, W4T,
                                       bi0, bh0, bi1, bh1, bi2, bh2,
                                       bik0, bhk0, bik1, bhk1, Wo, bo,
                                       (float*)d_out);
}